// Round 5
// baseline (48.221 us; speedup 1.0000x reference)
//
#include <hip/hip_runtime.h>

#define NATOMS 25000
#define NSP 64
#define NRANGE 8
#define RSIZE ((NATOMS + NRANGE - 1) / NRANGE)   // 3125 atoms per range (exact)
#define NWAVE 8
#define WSUB ((RSIZE + NWAVE - 1) / NWAVE)       // 391 atoms per wave
#define WIT ((WSUB + 63) / 64)                   // 7 scan iters per wave
#define LCAP (WIT * 64)                          // 448

typedef short bf16x8 __attribute__((ext_vector_type(8)));   // 8 bf16 = 4 VGPRs
typedef float f32x4  __attribute__((ext_vector_type(4)));
typedef unsigned short u16;

// f32 -> bf16 round-to-nearest-even
__device__ __forceinline__ u16 f2bf(float f) {
  unsigned u = __float_as_uint(f);
  u += 0x7fffu + ((u >> 16) & 1u);
  return (u16)(u >> 16);
}

__global__ __launch_bounds__(512, 4)
void zcl_kernel(const float* __restrict__ feat,
                const int*   __restrict__ sp,
                const float* __restrict__ weight,
                const float* __restrict__ bias,
                float*       __restrict__ out)
{
  // W[o][i] bf16, rows of 128; 16B chunks XOR-swizzled by (row&7) so B-frag
  // ds_read_b128 (lanes differ in row, fixed k-chunk) spreads all 32 banks.
  __shared__ u16 Ws[128 * 128];        // 32 KiB
  __shared__ u16 wlist[NWAVE][LCAP];   // 7 KiB, wave-private lists

  const int tid = threadIdx.x;
  const int bid = blockIdx.x;
  // XCD-aware decode: blocks u = r*64 + s -> XCD u%8 = s%8, so all 8 ranges
  // of one species share an XCD; W working set/XCD = 8 species * 64KB = 512KB
  // (L2-resident re-pulls).
  const int s  = bid & 63;             // species
  const int r  = bid >> 6;             // atom range
  const int lo = r * RSIZE;
  const int hi = (lo + RSIZE < NATOMS) ? (lo + RSIZE) : NATOMS;

  const int wv   = tid >> 6;           // 0..7
  const int lane = tid & 63;
  const int l16  = lane & 15;
  const int kq   = (lane >> 4) & 3;
  const int wlo  = lo + wv * WSUB;
  const int whi  = (wlo + WSUB < hi) ? (wlo + WSUB) : hi;

  // ---- 1) sp preload first (oldest in VMEM queue, completes first) ----
  int spv[WIT];
  #pragma unroll
  for (int i = 0; i < WIT; ++i) {
    int a = wlo + i * 64 + lane;
    spv[i] = (a < whi) ? sp[a] : -1;
  }

  // bias hoist (L2-hot)
  float bvb[8];
  #pragma unroll
  for (int nf = 0; nf < 8; ++nf) bvb[nf] = bias[s * 128 + l16 + 16 * nf];

  // ---- 2) issue W[s] loads: 4 chunks/thread = 32 VGPRs, stay in flight ----
  const float4* wg = (const float4*)(weight + (size_t)s * (128 * 128));
  float4 w0[4], w1[4];
  #pragma unroll
  for (int j = 0; j < 4; ++j) {
    int m = j * 512 + tid;             // chunk 0..2047: row=m>>4, 8-group c=m&15
    int row = m >> 4, c = m & 15;
    w0[j] = wg[row * 32 + c * 2];
    w1[j] = wg[row * 32 + c * 2 + 1];
  }

  // ---- 3) wave-private compact scan (no atomics, no barriers);
  //         counted vmcnt leaves W loads in flight while scanning ----
  int wcnt = 0;
  #pragma unroll
  for (int i = 0; i < WIT; ++i) {
    bool m = (spv[i] == s);
    unsigned long long mk = __ballot(m);
    if (m) wlist[wv][wcnt + __popcll(mk & ((1ull << lane) - 1ull))] =
             (u16)(wlo + i * 64 + lane);
    wcnt += (int)__popcll(mk);
  }
  const int nt = (wcnt + 15) >> 4;

  // ---- 4) prefetch A for this wave's tile 0 (overlaps W drain + convert) ----
  float4 pf[8];
  if (nt > 0) {
    int atomA = wlist[wv][l16 < wcnt ? l16 : 0];
    const float4* xg = (const float4*)(feat + (size_t)atomA * 128);
    #pragma unroll
    for (int ks = 0; ks < 4; ++ks) {
      pf[2 * ks]     = xg[ks * 8 + kq * 2];
      pf[2 * ks + 1] = xg[ks * 8 + kq * 2 + 1];
    }
  }

  // ---- 5) convert W -> bf16, swizzled ds_write ----
  #pragma unroll
  for (int j = 0; j < 4; ++j) {
    int m = j * 512 + tid;
    int row = m >> 4, c = m & 15;
    union { u16 h[8]; bf16x8 v; } uu;
    uu.h[0] = f2bf(w0[j].x); uu.h[1] = f2bf(w0[j].y);
    uu.h[2] = f2bf(w0[j].z); uu.h[3] = f2bf(w0[j].w);
    uu.h[4] = f2bf(w1[j].x); uu.h[5] = f2bf(w1[j].y);
    uu.h[6] = f2bf(w1[j].z); uu.h[7] = f2bf(w1[j].w);
    *(bf16x8*)&Ws[row * 128 + ((c ^ (row & 7)) << 3)] = uu.v;
  }

  __syncthreads();   // Ws visible to all waves

  // ---- 6) wave-independent tile loop (16 atoms x 128 outs x K=128) ----
  for (int t = 0; t < nt; ++t) {
    bf16x8 av[4];
    #pragma unroll
    for (int ks = 0; ks < 4; ++ks) {
      union { u16 h[8]; bf16x8 v; } uu;
      uu.h[0] = f2bf(pf[2 * ks].x);     uu.h[1] = f2bf(pf[2 * ks].y);
      uu.h[2] = f2bf(pf[2 * ks].z);     uu.h[3] = f2bf(pf[2 * ks].w);
      uu.h[4] = f2bf(pf[2 * ks + 1].x); uu.h[5] = f2bf(pf[2 * ks + 1].y);
      uu.h[6] = f2bf(pf[2 * ks + 1].z); uu.h[7] = f2bf(pf[2 * ks + 1].w);
      av[ks] = uu.v;
    }

    if (t + 1 < nt) {   // prefetch next tile, overlaps MFMA + stores
      int li = (t + 1) * 16 + l16;
      int atomA = wlist[wv][li < wcnt ? li : 0];
      const float4* xg = (const float4*)(feat + (size_t)atomA * 128);
      #pragma unroll
      for (int ks = 0; ks < 4; ++ks) {
        pf[2 * ks]     = xg[ks * 8 + kq * 2];
        pf[2 * ks + 1] = xg[ks * 8 + kq * 2 + 1];
      }
    }

    f32x4 acc[8];
    #pragma unroll
    for (int nf = 0; nf < 8; ++nf) acc[nf] = (f32x4){0.f, 0.f, 0.f, 0.f};
    #pragma unroll
    for (int ks = 0; ks < 4; ++ks) {
      int chunk = ((ks * 4 + kq) ^ (l16 & 7)) << 3;   // row&7 == l16&7 for all nf
      #pragma unroll
      for (int nf = 0; nf < 8; ++nf) {
        bf16x8 b = *(const bf16x8*)&Ws[(l16 + 16 * nf) * 128 + chunk];
        acc[nf] = __builtin_amdgcn_mfma_f32_16x16x32_bf16(av[ks], b, acc[nf], 0, 0, 0);
      }
    }

    // store: D row = kq*4+q -> atom; col = l16 -> out channel l16+16*nf
    #pragma unroll
    for (int q = 0; q < 4; ++q) {
      int li2 = t * 16 + kq * 4 + q;
      if (li2 < wcnt) {
        int atom = wlist[wv][li2];
        float* op = out + (size_t)atom * 128 + l16;
        #pragma unroll
        for (int nf = 0; nf < 8; ++nf) op[16 * nf] = acc[nf][q] + bvb[nf];
      }
    }
  }
}

extern "C" void kernel_launch(void* const* d_in, const int* in_sizes, int n_in,
                              void* d_out, int out_size, void* d_ws, size_t ws_size,
                              hipStream_t stream) {
  const float* feat   = (const float*)d_in[0];
  const int*   sp     = (const int*)d_in[1];
  const float* weight = (const float*)d_in[2];
  const float* bias   = (const float*)d_in[3];
  float*       out    = (float*)d_out;
  zcl_kernel<<<NSP * NRANGE, 512, 0, stream>>>(feat, sp, weight, bias, out);
}

// Round 6
// 36.968 us; speedup vs baseline: 1.3044x; 1.3044x over previous
//
#include <hip/hip_runtime.h>

#define NATOMS 25000
#define NSP 64
#define NRANGE 16
#define RSIZE ((NATOMS + NRANGE - 1) / NRANGE)   // 1563 atoms per range
#define SCAN_IT ((RSIZE + 255) / 256)            // 7
#define LCAP ((RSIZE + 31) & ~31)                // 1568 (worst case all match)

typedef short bf16x8 __attribute__((ext_vector_type(8)));   // 8 bf16 = 4 VGPRs
typedef float f32x4  __attribute__((ext_vector_type(4)));
typedef unsigned short u16;

// f32 -> bf16 round-to-nearest-even
__device__ __forceinline__ u16 f2bf(float f) {
  unsigned u = __float_as_uint(f);
  u += 0x7fffu + ((u >> 16) & 1u);
  return (u16)(u >> 16);
}

__global__ __launch_bounds__(256, 4)   // VGPR cap 128 (4 waves/SIMD target)
void zcl_kernel(const float* __restrict__ feat,
                const int*   __restrict__ sp,
                const float* __restrict__ weight,
                const float* __restrict__ bias,
                float*       __restrict__ out)
{
  // W[o][i] bf16, rows of 128; 16B chunks XOR-swizzled by (row&7) so B-frag
  // ds_read_b128 (lanes differ in row, fixed k-chunk) spreads banks evenly.
  __shared__ u16 Ws[128 * 128];   // 32 KiB
  __shared__ u16 list[LCAP];      // 3.1 KiB
  __shared__ int nM;              // total ~35.2 KiB -> 4 blocks/CU

  const int tid = threadIdx.x;
  const int bid = blockIdx.x;
  // XCD-aware decode (bid%8 == XCD): 8 species pinned per XCD -> W f32
  // working set 8*64KB = 512KB, L2-resident for 15/16 of blocks.
  const int xcd = bid & 7;
  const int jj  = bid >> 3;              // 0..127
  const int s   = xcd + 8 * (jj & 7);    // species 0..63
  const int r   = jj >> 3;               // range 0..15
  const int lo  = r * RSIZE;
  const int hi  = (lo + RSIZE < NATOMS) ? (lo + RSIZE) : NATOMS;

  const int wv   = tid >> 6;
  const int lane = tid & 63;
  const int l16  = lane & 15;
  const int kq   = lane >> 4;

  // ---- 1) sp preload first (oldest in VMEM queue, completes first) ----
  int spv[SCAN_IT];
  #pragma unroll
  for (int i = 0; i < SCAN_IT; ++i) {
    int a = lo + i * 256 + tid;
    spv[i] = (a < hi) ? sp[a] : -1;
  }

  // bias hoist (L2-hot)
  float bvb[8];
  #pragma unroll
  for (int nf = 0; nf < 8; ++nf) bvb[nf] = bias[s * 128 + l16 + 16 * nf];

  // ---- 2) W staging round 0: chunks 0..1023, 8 float4 = 32 VGPRs ----
  const float4* wg = (const float4*)(weight + (size_t)s * (128 * 128));
  float4 wA[8];
  #pragma unroll
  for (int q = 0; q < 4; ++q) {
    int m = q * 256 + tid;               // chunk: row=m>>4, 8-elem group c=m&15
    int row = m >> 4, c = m & 15;
    wA[2 * q]     = wg[row * 32 + c * 2];
    wA[2 * q + 1] = wg[row * 32 + c * 2 + 1];
  }

  // ---- 3) nM init; raw barrier (lgkm-only, W loads stay in flight) ----
  if (tid == 0) nM = 0;
  asm volatile("s_waitcnt lgkmcnt(0)" ::: "memory");
  __builtin_amdgcn_s_barrier();
  __builtin_amdgcn_sched_barrier(0);

  // ---- 4) block-shared compact scan (overlaps W round-0 arrival) ----
  #pragma unroll
  for (int i = 0; i < SCAN_IT; ++i) {
    bool m = (spv[i] == s);
    unsigned long long mk = __ballot(m);
    int base = 0;
    if (lane == 0) base = atomicAdd(&nM, (int)__popcll(mk));
    base = __shfl(base, 0);
    if (m) list[base + __popcll(mk & ((1ull << lane) - 1ull))] =
             (u16)(lo + i * 256 + tid);
  }

  // ---- 5) convert round 0 -> LDS; then round 1 (reuse regs) -> LDS ----
  #pragma unroll
  for (int q = 0; q < 4; ++q) {
    int m = q * 256 + tid;
    int row = m >> 4, c = m & 15;
    union { u16 h[8]; bf16x8 v; } uu;
    uu.h[0] = f2bf(wA[2 * q].x);     uu.h[1] = f2bf(wA[2 * q].y);
    uu.h[2] = f2bf(wA[2 * q].z);     uu.h[3] = f2bf(wA[2 * q].w);
    uu.h[4] = f2bf(wA[2 * q + 1].x); uu.h[5] = f2bf(wA[2 * q + 1].y);
    uu.h[6] = f2bf(wA[2 * q + 1].z); uu.h[7] = f2bf(wA[2 * q + 1].w);
    *(bf16x8*)&Ws[row * 128 + ((c ^ (row & 7)) << 3)] = uu.v;
  }
  #pragma unroll
  for (int q = 0; q < 4; ++q) {        // round 1: chunks 1024..2047 (L2-hot)
    int m = 1024 + q * 256 + tid;
    int row = m >> 4, c = m & 15;
    wA[2 * q]     = wg[row * 32 + c * 2];
    wA[2 * q + 1] = wg[row * 32 + c * 2 + 1];
  }
  #pragma unroll
  for (int q = 0; q < 4; ++q) {
    int m = 1024 + q * 256 + tid;
    int row = m >> 4, c = m & 15;
    union { u16 h[8]; bf16x8 v; } uu;
    uu.h[0] = f2bf(wA[2 * q].x);     uu.h[1] = f2bf(wA[2 * q].y);
    uu.h[2] = f2bf(wA[2 * q].z);     uu.h[3] = f2bf(wA[2 * q].w);
    uu.h[4] = f2bf(wA[2 * q + 1].x); uu.h[5] = f2bf(wA[2 * q + 1].y);
    uu.h[6] = f2bf(wA[2 * q + 1].z); uu.h[7] = f2bf(wA[2 * q + 1].w);
    *(bf16x8*)&Ws[row * 128 + ((c ^ (row & 7)) << 3)] = uu.v;
  }

  __syncthreads();   // Ws + list + nM visible

  const int nMatch = nM;
  const int ntile  = (nMatch + 15) >> 4;
  if (ntile == 0) return;

  // ---- 6) tiles t = wv, wv+4, ... (16 atoms x 128 outs x K=128 each) ----
  int t = wv;
  float4 pf[8];
  if (t < ntile) {
    int li = t * 16 + l16;
    int atomA = list[li < nMatch ? li : 0];
    const float4* xg = (const float4*)(feat + (size_t)atomA * 128);
    #pragma unroll
    for (int ks = 0; ks < 4; ++ks) {
      pf[2 * ks]     = xg[ks * 8 + kq * 2];
      pf[2 * ks + 1] = xg[ks * 8 + kq * 2 + 1];
    }
  }

  for (; t < ntile; t += 4) {
    // convert current A (consumes pf) before overwriting with prefetch
    bf16x8 av[4];
    #pragma unroll
    for (int ks = 0; ks < 4; ++ks) {
      union { u16 h[8]; bf16x8 v; } uu;
      uu.h[0] = f2bf(pf[2 * ks].x);     uu.h[1] = f2bf(pf[2 * ks].y);
      uu.h[2] = f2bf(pf[2 * ks].z);     uu.h[3] = f2bf(pf[2 * ks].w);
      uu.h[4] = f2bf(pf[2 * ks + 1].x); uu.h[5] = f2bf(pf[2 * ks + 1].y);
      uu.h[6] = f2bf(pf[2 * ks + 1].z); uu.h[7] = f2bf(pf[2 * ks + 1].w);
      av[ks] = uu.v;
    }

    if (t + 4 < ntile) {   // prefetch next tile (overlaps MFMA + stores)
      int li = (t + 4) * 16 + l16;
      int atomA = list[li < nMatch ? li : 0];
      const float4* xg = (const float4*)(feat + (size_t)atomA * 128);
      #pragma unroll
      for (int ks = 0; ks < 4; ++ks) {
        pf[2 * ks]     = xg[ks * 8 + kq * 2];
        pf[2 * ks + 1] = xg[ks * 8 + kq * 2 + 1];
      }
    }

    f32x4 acc[8];
    #pragma unroll
    for (int nf = 0; nf < 8; ++nf) acc[nf] = (f32x4){0.f, 0.f, 0.f, 0.f};
    #pragma unroll
    for (int ks = 0; ks < 4; ++ks) {
      int chunk = ((ks * 4 + kq) ^ (l16 & 7)) << 3;   // row&7 == l16&7 all nf
      #pragma unroll
      for (int nf = 0; nf < 8; ++nf) {
        bf16x8 b = *(const bf16x8*)&Ws[(l16 + 16 * nf) * 128 + chunk];
        acc[nf] = __builtin_amdgcn_mfma_f32_16x16x32_bf16(av[ks], b, acc[nf], 0, 0, 0);
      }
    }

    // store: D row = kq*4+q -> atom; col = l16 -> out channel l16+16*nf
    #pragma unroll
    for (int q = 0; q < 4; ++q) {
      int li2 = t * 16 + kq * 4 + q;
      if (li2 < nMatch) {
        int atom = list[li2];
        float* op = out + (size_t)atom * 128 + l16;
        #pragma unroll
        for (int nf = 0; nf < 8; ++nf) op[16 * nf] = acc[nf][q] + bvb[nf];
      }
    }
  }
}

extern "C" void kernel_launch(void* const* d_in, const int* in_sizes, int n_in,
                              void* d_out, int out_size, void* d_ws, size_t ws_size,
                              hipStream_t stream) {
  const float* feat   = (const float*)d_in[0];
  const int*   sp     = (const int*)d_in[1];
  const float* weight = (const float*)d_in[2];
  const float* bias   = (const float*)d_in[3];
  float*       out    = (float*)d_out;
  zcl_kernel<<<NSP * NRANGE, 256, 0, stream>>>(feat, sp, weight, bias, out);
}

// Round 7
// 20.568 us; speedup vs baseline: 2.3445x; 1.7974x over previous
//
#include <hip/hip_runtime.h>

#define NATOMS 25000
#define NSP 64
#define LISTCAP 1024
#define NBLK_A ((NATOMS + 255) / 256)   // 98 list-building blocks

typedef short bf16x8 __attribute__((ext_vector_type(8)));   // 8 bf16 = 4 VGPRs
typedef float f32x4  __attribute__((ext_vector_type(4)));
typedef unsigned short u16;
typedef __attribute__((address_space(3))) unsigned int lds_u32;
typedef __attribute__((address_space(1))) unsigned int gbl_u32;

// f32 -> bf16 round-to-nearest-even
__device__ __forceinline__ u16 f2bf(float f) {
  unsigned u = __float_as_uint(f);
  u += 0x7fffu + ((u >> 16) & 1u);
  return (u16)(u >> 16);
}

// ws layout: [0,2MiB) W bf16 | [2MiB,+256B) cnt[64] | [2MiB+4KiB,+256KiB) lists[64][1024]

// ---- prep: W f32->bf16 (all 512 blocks) + packed species lists (blocks 0..97) ----
__global__ __launch_bounds__(256)
void prep_kernel(const float* __restrict__ w, const int* __restrict__ sp,
                 u16* __restrict__ wbf, int* __restrict__ cnt, int* __restrict__ lists)
{
  __shared__ int lh[NSP];     // block-local histogram
  __shared__ int lbase[NSP];  // global base per species for this block
  const int tid = threadIdx.x, bid = blockIdx.x;
  const int g = bid * 256 + tid;

  // W convert: 8 elems/thread, fully sequential read+write
  const float4* p = (const float4*)w + (size_t)g * 2;
  float4 v0 = p[0], v1 = p[1];
  union { u16 h[8]; bf16x8 v; } uu;
  uu.h[0] = f2bf(v0.x); uu.h[1] = f2bf(v0.y);
  uu.h[2] = f2bf(v0.z); uu.h[3] = f2bf(v0.w);
  uu.h[4] = f2bf(v1.x); uu.h[5] = f2bf(v1.y);
  uu.h[6] = f2bf(v1.z); uu.h[7] = f2bf(v1.w);
  ((bf16x8*)wbf)[g] = uu.v;

  // packed lists: LDS histogram -> one global atomic per species -> scatter
  if (bid < NBLK_A) {
    if (tid < NSP) lh[tid] = 0;
    __syncthreads();
    int a = g, s = 0, lpos = 0;
    bool valid = (a < NATOMS);
    if (valid) { s = sp[a]; lpos = atomicAdd(&lh[s], 1); }
    __syncthreads();
    if (tid < NSP) lbase[tid] = atomicAdd(&cnt[tid], lh[tid]);
    __syncthreads();
    if (valid) lists[s * LISTCAP + lbase[s] + lpos] = a;
  }
}

// ---- main: 512 blocks = 64 species x 8 slices; each wave = one 16-atom tile ----
__global__ __launch_bounds__(256)
void zcl_main(const float* __restrict__ feat, const u16* __restrict__ wbf,
              const float* __restrict__ bias, const int* __restrict__ cnt,
              const int* __restrict__ lists, float* __restrict__ out)
{
  // W[o][i] bf16 in LDS, 16B chunks XOR-swizzled by (row&7); staged via
  // global_load_lds with the swizzle pre-applied on the global source (m173).
  __shared__ u16 Ws[128 * 128];   // 32 KiB -> 2 blocks/CU at grid 512

  const int tid = threadIdx.x, bid = blockIdx.x;
  // XCD swizzle: all 8 slices of species s share XCD s%8 (W bf16 L2-hot)
  const int xcd = bid & 7, qq = bid >> 3;
  const int s = xcd + 8 * (qq & 7);
  const int j = qq >> 3;                 // slice 0..7
  const int wv = tid >> 6, lane = tid & 63;
  const int l16 = lane & 15, kq = lane >> 4;

  // 1) issue async W stage first (oldest in VMEM queue; zero VGPR cost)
  const u16* wsrc = wbf + (size_t)s * 16384;
  #pragma unroll
  for (int rnd = 0; rnd < 8; ++rnd) {
    int m = rnd * 256 + tid, row = m >> 4, c = m & 15;
    const u16* src = wsrc + row * 128 + ((c ^ (row & 7)) << 3);
    u16* dst = &Ws[(rnd * 256 + (tid & ~63)) * 8];   // linear, wave-uniform base
    __builtin_amdgcn_global_load_lds((gbl_u32*)src, (lds_u32*)dst, 16, 0, 0);
  }

  // 2) independent loads issued together (one round trip): cnt, list, bias
  const int cntS = cnt[s];
  const int t  = j + 8 * wv;             // this wave's tile (slots 0..31 >= ntile max 29)
  const int li = t * 16 + l16;           // <= 511 < LISTCAP, always in-bounds
  const int specA = lists[s * LISTCAP + li];
  const int d0    = lists[s * LISTCAP];  // fallback valid atom (broadcast load)
  float bvb[8];
  #pragma unroll
  for (int nf = 0; nf < 8; ++nf) bvb[nf] = bias[s * 128 + l16 + 16 * nf];

  if (cntS == 0) return;                 // block-uniform (never for this input)
  const bool run = (t * 16 < cntS);      // wave-uniform tile guard

  // 3) feat gather for my A-row (2nd round trip)
  int a0 = (li < cntS) ? specA : d0;
  float4 pf[8];
  if (run) {
    const float4* xg = (const float4*)(feat + (size_t)a0 * 128);
    #pragma unroll
    for (int ks = 0; ks < 4; ++ks) {
      pf[2 * ks]     = xg[ks * 8 + kq * 2];
      pf[2 * ks + 1] = xg[ks * 8 + kq * 2 + 1];
    }
  }

  __syncthreads();   // drains each wave's vmcnt (incl. gll) + barrier: Ws ready
  if (!run) return;

  // 4) convert A, 32 MFMA (16 atoms x 128 outs x K=128), store
  bf16x8 av[4];
  #pragma unroll
  for (int ks = 0; ks < 4; ++ks) {
    union { u16 h[8]; bf16x8 v; } uu;
    uu.h[0] = f2bf(pf[2 * ks].x);     uu.h[1] = f2bf(pf[2 * ks].y);
    uu.h[2] = f2bf(pf[2 * ks].z);     uu.h[3] = f2bf(pf[2 * ks].w);
    uu.h[4] = f2bf(pf[2 * ks + 1].x); uu.h[5] = f2bf(pf[2 * ks + 1].y);
    uu.h[6] = f2bf(pf[2 * ks + 1].z); uu.h[7] = f2bf(pf[2 * ks + 1].w);
    av[ks] = uu.v;
  }

  f32x4 acc[8];
  #pragma unroll
  for (int nf = 0; nf < 8; ++nf) acc[nf] = (f32x4){0.f, 0.f, 0.f, 0.f};
  #pragma unroll
  for (int ks = 0; ks < 4; ++ks) {
    int chunk = ((ks * 4 + kq) ^ (l16 & 7)) << 3;   // row&7 == l16&7 for all nf
    #pragma unroll
    for (int nf = 0; nf < 8; ++nf) {
      bf16x8 b = *(const bf16x8*)&Ws[(l16 + 16 * nf) * 128 + chunk];
      acc[nf] = __builtin_amdgcn_mfma_f32_16x16x32_bf16(av[ks], b, acc[nf], 0, 0, 0);
    }
  }

  // store: D row = kq*4+qr -> atom (id via shfl from lane rr), col = l16
  #pragma unroll
  for (int qr = 0; qr < 4; ++qr) {
    int rr = kq * 4 + qr;
    int a_row = __shfl(a0, rr);          // lane rr holds row rr's atom id
    if (t * 16 + rr < cntS) {
      float* op = out + (size_t)a_row * 128 + l16;
      #pragma unroll
      for (int nf = 0; nf < 8; ++nf) op[16 * nf] = acc[nf][qr] + bvb[nf];
    }
  }
}

extern "C" void kernel_launch(void* const* d_in, const int* in_sizes, int n_in,
                              void* d_out, int out_size, void* d_ws, size_t ws_size,
                              hipStream_t stream) {
  const float* feat   = (const float*)d_in[0];
  const int*   sp     = (const int*)d_in[1];
  const float* weight = (const float*)d_in[2];
  const float* bias   = (const float*)d_in[3];
  float*       out    = (float*)d_out;

  char* base = (char*)d_ws;
  u16*  wbf   = (u16*)base;                         // 2 MiB
  int*  cnt   = (int*)(base + (2u << 20));          // 256 B
  int*  lists = (int*)(base + (2u << 20) + 4096);   // 256 KiB

  hipMemsetAsync(cnt, 0, NSP * sizeof(int), stream);
  prep_kernel<<<512, 256, 0, stream>>>(weight, sp, wbf, cnt, lists);
  zcl_main<<<NSP * 8, 256, 0, stream>>>(feat, wbf, bias, cnt, lists, out);
}

// Round 8
// 18.408 us; speedup vs baseline: 2.6196x; 1.1173x over previous
//
#include <hip/hip_runtime.h>

#define NATOMS 25000
#define NSP 64
#define NRANGE 8
#define RSIZE ((NATOMS + NRANGE - 1) / NRANGE)   // 3125 atoms per range
#define NWAVE 4
#define WSUB ((RSIZE + NWAVE - 1) / NWAVE)       // 782 atoms per wave
#define WIT ((WSUB + 63) / 64)                   // 13 scan iters per wave
#define LCAP (WIT * 64)                          // 832

typedef short bf16x8 __attribute__((ext_vector_type(8)));   // 8 bf16 = 4 VGPRs
typedef float f32x4  __attribute__((ext_vector_type(4)));
typedef unsigned short u16;
typedef __attribute__((address_space(3))) unsigned int lds_u32;
typedef __attribute__((address_space(1))) unsigned int gbl_u32;

// f32 -> bf16 round-to-nearest-even
__device__ __forceinline__ u16 f2bf(float f) {
  unsigned u = __float_as_uint(f);
  u += 0x7fffu + ((u >> 16) & 1u);
  return (u16)(u >> 16);
}

// ---- prep: W f32 -> bf16, plain [s][o][i]. 512 blocks x 256 thr x 8 elems ----
__global__ __launch_bounds__(256)
void conv_w(const float* __restrict__ w, u16* __restrict__ wbf) {
  int g = blockIdx.x * 256 + threadIdx.x;
  const float4* p = (const float4*)w + (size_t)g * 2;
  float4 v0 = p[0], v1 = p[1];
  union { u16 h[8]; bf16x8 v; } uu;
  uu.h[0] = f2bf(v0.x); uu.h[1] = f2bf(v0.y);
  uu.h[2] = f2bf(v0.z); uu.h[3] = f2bf(v0.w);
  uu.h[4] = f2bf(v1.x); uu.h[5] = f2bf(v1.y);
  uu.h[6] = f2bf(v1.z); uu.h[7] = f2bf(v1.w);
  ((bf16x8*)wbf)[g] = uu.v;
}

// ---- main: 512 blocks = 64 species x 8 ranges, wave-private scan ----
__global__ __launch_bounds__(256)
void zcl_main(const float* __restrict__ feat, const int* __restrict__ sp,
              const u16* __restrict__ wbf, const float* __restrict__ bias,
              float* __restrict__ out)
{
  // W[o][i] bf16 in LDS, 16B chunks XOR-swizzled by (row&7); swizzle applied
  // on the per-lane GLOBAL source (m173), LDS dest stays linear.
  __shared__ u16 Ws[128 * 128];        // 32 KiB
  __shared__ u16 wlist[NWAVE][LCAP];   // 6.5 KiB, wave-private lists

  const int tid = threadIdx.x, bid = blockIdx.x;
  // XCD swizzle: species s pinned to XCD s%8 -> W bf16 working set per XCD
  // = 8 species x 32KB = 256KB, L2-resident after the first range touches it.
  const int s = (bid & 7) + 8 * ((bid >> 3) & 7);
  const int r = bid >> 6;
  const int lo = r * RSIZE;
  const int hi = (lo + RSIZE < NATOMS) ? (lo + RSIZE) : NATOMS;

  const int wv = tid >> 6, lane = tid & 63;
  const int l16 = lane & 15, kq = lane >> 4;
  const int wlo = lo + wv * WSUB;
  const int whi = (wlo + WSUB < hi) ? (wlo + WSUB) : hi;

  // 1) sp preload FIRST (oldest in vmcnt FIFO -> scan's wait leaves W in flight)
  int spv[WIT];
  #pragma unroll
  for (int i = 0; i < WIT; ++i) {
    int a = wlo + i * 64 + lane;
    spv[i] = (a < whi) ? sp[a] : -1;
  }

  // 2) async W stage: 8x global_load_lds width-16, zero VGPR / zero VALU
  const u16* wsrc = wbf + (size_t)s * 16384;
  #pragma unroll
  for (int rnd = 0; rnd < 8; ++rnd) {
    int m = rnd * 256 + tid, row = m >> 4, c = m & 15;
    const u16* src = wsrc + row * 128 + ((c ^ (row & 7)) << 3);
    u16* dst = &Ws[(rnd * 256 + (tid & ~63)) * 8];   // linear, wave-uniform base
    __builtin_amdgcn_global_load_lds((gbl_u32*)src, (lds_u32*)dst, 16, 0, 0);
  }

  // 3) wave-private compact scan (no atomics, no barrier; waits sp only)
  int wcnt = 0;
  #pragma unroll
  for (int i = 0; i < WIT; ++i) {
    bool m = (spv[i] == s);
    unsigned long long mk = __ballot(m);
    if (m) wlist[wv][wcnt + __popcll(mk & ((1ull << lane) - 1ull))] =
             (u16)(wlo + i * 64 + lane);
    wcnt += (int)__popcll(mk);
  }
  const int nt = (wcnt + 15) >> 4;

  // 4) feat prefetch for tile 0 (overlaps W-stage drain)
  float4 pf[8];
  if (nt > 0) {
    int atomA = wlist[wv][l16 < wcnt ? l16 : 0];
    const float4* xg = (const float4*)(feat + (size_t)atomA * 128);
    #pragma unroll
    for (int ks = 0; ks < 4; ++ks) {
      pf[2 * ks]     = xg[ks * 8 + kq * 2];
      pf[2 * ks + 1] = xg[ks * 8 + kq * 2 + 1];
    }
  }

  __syncthreads();   // all waves' gll drained + wlist visible; Ws ready

  // bias (L2-hot, consumed at stores only)
  float bvb[8];
  #pragma unroll
  for (int nf = 0; nf < 8; ++nf) bvb[nf] = bias[s * 128 + l16 + 16 * nf];

  // 5) wave-independent tile loop (16 atoms x 128 outs x K=128)
  for (int t = 0; t < nt; ++t) {
    bf16x8 av[4];
    #pragma unroll
    for (int ks = 0; ks < 4; ++ks) {
      union { u16 h[8]; bf16x8 v; } uu;
      uu.h[0] = f2bf(pf[2 * ks].x);     uu.h[1] = f2bf(pf[2 * ks].y);
      uu.h[2] = f2bf(pf[2 * ks].z);     uu.h[3] = f2bf(pf[2 * ks].w);
      uu.h[4] = f2bf(pf[2 * ks + 1].x); uu.h[5] = f2bf(pf[2 * ks + 1].y);
      uu.h[6] = f2bf(pf[2 * ks + 1].z); uu.h[7] = f2bf(pf[2 * ks + 1].w);
      av[ks] = uu.v;
    }

    if (t + 1 < nt) {   // prefetch next tile (overlaps MFMA + stores)
      int li = (t + 1) * 16 + l16;
      int atomA = wlist[wv][li < wcnt ? li : 0];
      const float4* xg = (const float4*)(feat + (size_t)atomA * 128);
      #pragma unroll
      for (int ks = 0; ks < 4; ++ks) {
        pf[2 * ks]     = xg[ks * 8 + kq * 2];
        pf[2 * ks + 1] = xg[ks * 8 + kq * 2 + 1];
      }
    }

    f32x4 acc[8];
    #pragma unroll
    for (int nf = 0; nf < 8; ++nf) acc[nf] = (f32x4){0.f, 0.f, 0.f, 0.f};
    #pragma unroll
    for (int ks = 0; ks < 4; ++ks) {
      int chunk = ((ks * 4 + kq) ^ (l16 & 7)) << 3;   // row&7 == l16&7 for all nf
      #pragma unroll
      for (int nf = 0; nf < 8; ++nf) {
        bf16x8 b = *(const bf16x8*)&Ws[(l16 + 16 * nf) * 128 + chunk];
        acc[nf] = __builtin_amdgcn_mfma_f32_16x16x32_bf16(av[ks], b, acc[nf], 0, 0, 0);
      }
    }

    // store: D row = kq*4+q -> atom; col = l16 -> out channel l16+16*nf
    #pragma unroll
    for (int q = 0; q < 4; ++q) {
      int li2 = t * 16 + kq * 4 + q;
      if (li2 < wcnt) {
        int atom = wlist[wv][li2];
        float* op = out + (size_t)atom * 128 + l16;
        #pragma unroll
        for (int nf = 0; nf < 8; ++nf) op[16 * nf] = acc[nf][q] + bvb[nf];
      }
    }
  }
}

extern "C" void kernel_launch(void* const* d_in, const int* in_sizes, int n_in,
                              void* d_out, int out_size, void* d_ws, size_t ws_size,
                              hipStream_t stream) {
  const float* feat   = (const float*)d_in[0];
  const int*   sp     = (const int*)d_in[1];
  const float* weight = (const float*)d_in[2];
  const float* bias   = (const float*)d_in[3];
  float*       out    = (float*)d_out;
  u16*         wbf    = (u16*)d_ws;    // 2 MiB scratch

  conv_w<<<512, 256, 0, stream>>>(weight, wbf);
  zcl_main<<<NSP * NRANGE, 256, 0, stream>>>(feat, sp, wbf, bias, out);
}